// Round 1
// baseline (3552.061 us; speedup 1.0000x reference)
//
#include <hip/hip_runtime.h>

#define DIM 64
#define CLS 20

// ---------- degree: deg[dst] += 1 ----------
__global__ void deg_kernel(const int* __restrict__ edst, float* __restrict__ deg, int E) {
    int e = blockIdx.x * blockDim.x + threadIdx.x;
    if (e < E) atomicAdd(&deg[edst[e]], 1.0f);
}

// ---------- embedding lookup: h[n] = emb[tokens[n]] ----------
__global__ void embed_kernel(const int* __restrict__ tokens, const float* __restrict__ emb,
                             float* __restrict__ h, int N) {
    int t = blockIdx.x * blockDim.x + threadIdx.x;
    int n = t >> 4, c = t & 15;
    if (n < N) {
        int tok = tokens[n];
        ((float4*)h)[(size_t)n * 16 + c] = ((const float4*)emb)[(size_t)tok * 16 + c];
    }
}

// ---------- edge aggregation: agg[dst] += h[src] (16 lanes/edge, float4 each) ----------
__global__ void agg_kernel(const int* __restrict__ esrc, const int* __restrict__ edst,
                           const float* __restrict__ h, float* __restrict__ agg, int E) {
    int t = blockIdx.x * blockDim.x + threadIdx.x;
    int e = t >> 4, c = t & 15;
    if (e < E) {
        int s = esrc[e], d = edst[e];
        float4 v = ((const float4*)h)[(size_t)s * 16 + c];
        float* ap = &agg[(size_t)d * 64 + c * 4];
        atomicAdd(ap + 0, v.x);
        atomicAdd(ap + 1, v.y);
        atomicAdd(ap + 2, v.z);
        atomicAdd(ap + 3, v.w);
    }
}

// ---------- per-node GEMM + bias + relu: out[n] = relu(inv_deg[n]*(agg[n]@W) + b) ----------
__global__ void gemm_relu_kernel(const float* __restrict__ agg, const float* __restrict__ deg,
                                 const float* __restrict__ W, const float* __restrict__ b,
                                 float* __restrict__ out, int N) {
    __shared__ float Ws[64 * 64];
    __shared__ float bs[64];
    for (int i = threadIdx.x; i < 64 * 64; i += blockDim.x) Ws[i] = W[i];
    if (threadIdx.x < 64) bs[threadIdx.x] = b[threadIdx.x];
    __syncthreads();
    int gt = blockIdx.x * blockDim.x + threadIdx.x;
    int wave = gt >> 6, lane = threadIdx.x & 63;
    int nwaves = (gridDim.x * blockDim.x) >> 6;
    for (int n = wave; n < N; n += nwaves) {
        float a = agg[(size_t)n * 64 + lane];
        float inv = 1.0f / fmaxf(deg[n], 1.0f);
        float acc = 0.0f;
        #pragma unroll
        for (int k = 0; k < 64; ++k)
            acc += __shfl(a, k, 64) * Ws[k * 64 + lane];
        out[(size_t)n * 64 + lane] = fmaxf(fmaf(inv, acc, bs[lane]), 0.0f);
    }
}

// ---------- graph mean-pool accumulate ----------
__global__ void pool_kernel(const float* __restrict__ h, const int* __restrict__ gids,
                            float* __restrict__ pool, float* __restrict__ cnt, int N) {
    int t = blockIdx.x * blockDim.x + threadIdx.x;
    int n = t >> 6, lane = t & 63;
    if (n < N) {
        int g = gids[n];
        atomicAdd(&pool[(size_t)g * 64 + lane], h[(size_t)n * 64 + lane]);
        if (lane == 0) atomicAdd(&cnt[g], 1.0f);
    }
}

// ---------- classifier head: out[g][c] = (pool[g]/cnt[g]) @ Wc + bc ----------
__global__ void head_kernel(const float* __restrict__ pool, const float* __restrict__ cnt,
                            const float* __restrict__ Wc, const float* __restrict__ bc,
                            float* __restrict__ out, int G) {
    int t = blockIdx.x * blockDim.x + threadIdx.x;
    if (t < G * CLS) {
        int g = t / CLS, c = t % CLS;
        float ic = 1.0f / fmaxf(cnt[g], 1.0f);
        float s = 0.0f;
        #pragma unroll
        for (int k = 0; k < 64; ++k) s += pool[(size_t)g * 64 + k] * Wc[k * CLS + c];
        out[t] = fmaf(ic, s, bc[c]);
    }
}

extern "C" void kernel_launch(void* const* d_in, const int* in_sizes, int n_in,
                              void* d_out, int out_size, void* d_ws, size_t ws_size,
                              hipStream_t stream) {
    const int*   tokens = (const int*)d_in[0];
    const int*   esrc   = (const int*)d_in[1];
    const int*   edst   = (const int*)d_in[2];
    const int*   gids   = (const int*)d_in[3];
    const float* emb    = (const float*)d_in[4];
    const float* W1     = (const float*)d_in[5];
    const float* b1     = (const float*)d_in[6];
    const float* W2     = (const float*)d_in[7];
    const float* b2     = (const float*)d_in[8];
    const float* Wc     = (const float*)d_in[9];
    const float* bc     = (const float*)d_in[10];
    int N = in_sizes[0];
    int E = in_sizes[1];
    int G = out_size / CLS;
    float* out = (float*)d_out;

    // workspace layout (floats): h[N*64] | agg[N*64] | deg[N] | pool[G*64] | cnt[G]
    float* h    = (float*)d_ws;
    float* agg  = h + (size_t)N * 64;
    float* deg  = agg + (size_t)N * 64;
    float* pool = deg + N;
    float* cnt  = pool + (size_t)G * 64;

    hipMemsetAsync(agg, 0, (size_t)N * 64 * sizeof(float), stream);
    // deg, pool, cnt are contiguous -> one memset
    hipMemsetAsync(deg, 0, ((size_t)N + (size_t)G * 65) * sizeof(float), stream);

    deg_kernel<<<(E + 255) / 256, 256, 0, stream>>>(edst, deg, E);
    embed_kernel<<<(N * 16 + 255) / 256, 256, 0, stream>>>(tokens, emb, h, N);

    // layer 1
    agg_kernel<<<(E * 16 + 255) / 256, 256, 0, stream>>>(esrc, edst, h, agg, E);
    gemm_relu_kernel<<<1024, 256, 0, stream>>>(agg, deg, W1, b1, h, N);

    // layer 2
    hipMemsetAsync(agg, 0, (size_t)N * 64 * sizeof(float), stream);
    agg_kernel<<<(E * 16 + 255) / 256, 256, 0, stream>>>(esrc, edst, h, agg, E);
    gemm_relu_kernel<<<1024, 256, 0, stream>>>(agg, deg, W2, b2, h, N);

    // pooling + head
    pool_kernel<<<(N * 64 + 255) / 256, 256, 0, stream>>>(h, gids, pool, cnt, N);
    head_kernel<<<(G * CLS + 255) / 256, 256, 0, stream>>>(pool, cnt, Wc, bc, out, G);
}

// Round 4
// 512.809 us; speedup vs baseline: 6.9267x; 6.9267x over previous
//
#include <hip/hip_runtime.h>

#define DIM 64
#define CLS 20
#define SCAN_T 256
#define SCAN_E 1024   // elements per scan block (4 per thread)

// ---------- degree count (int) ----------
__global__ void deg_count_kernel(const int* __restrict__ edst, int* __restrict__ deg, int E) {
    int e = blockIdx.x * blockDim.x + threadIdx.x;
    if (e < E) atomicAdd(&deg[edst[e]], 1);
}

// ---------- exclusive scan, step 1: per-block ----------
__global__ void scan1_kernel(const int* __restrict__ deg, int* __restrict__ rp,
                             int* __restrict__ bsum, int N) {
    __shared__ int sh[SCAN_T];
    int base = blockIdx.x * SCAN_E + threadIdx.x * 4;
    int v0 = (base + 0 < N) ? deg[base + 0] : 0;
    int v1 = (base + 1 < N) ? deg[base + 1] : 0;
    int v2 = (base + 2 < N) ? deg[base + 2] : 0;
    int v3 = (base + 3 < N) ? deg[base + 3] : 0;
    sh[threadIdx.x] = v0 + v1 + v2 + v3;
    __syncthreads();
    for (int off = 1; off < SCAN_T; off <<= 1) {
        int t = (threadIdx.x >= off) ? sh[threadIdx.x - off] : 0;
        __syncthreads();
        sh[threadIdx.x] += t;
        __syncthreads();
    }
    int run = (threadIdx.x > 0) ? sh[threadIdx.x - 1] : 0;
    if (base + 0 < N) rp[base + 0] = run; run += v0;
    if (base + 1 < N) rp[base + 1] = run; run += v1;
    if (base + 2 < N) rp[base + 2] = run; run += v2;
    if (base + 3 < N) rp[base + 3] = run;
    if (threadIdx.x == SCAN_T - 1) bsum[blockIdx.x] = sh[SCAN_T - 1];
}

// ---------- scan step 2: scan of block sums (single block, NB <= 128) ----------
__global__ void scan2_kernel(int* __restrict__ bsum, int NB) {
    __shared__ int sh[128];
    int v = (threadIdx.x < NB) ? bsum[threadIdx.x] : 0;
    sh[threadIdx.x] = v;
    __syncthreads();
    for (int off = 1; off < 128; off <<= 1) {
        int t = (threadIdx.x >= off) ? sh[threadIdx.x - off] : 0;
        __syncthreads();
        sh[threadIdx.x] += t;
        __syncthreads();
    }
    if (threadIdx.x < NB) bsum[threadIdx.x] = sh[threadIdx.x] - v;  // exclusive
}

// ---------- scan step 3: add block offsets ----------
__global__ void scan3_kernel(int* __restrict__ rp, const int* __restrict__ bsum, int N) {
    int i = blockIdx.x * blockDim.x + threadIdx.x;
    if (i < N) rp[i] += bsum[i >> 10];
}

// ---------- CSR scatter: cursor starts as copy of row_ptr ----------
__global__ void scatter_kernel(const int* __restrict__ esrc, const int* __restrict__ edst,
                               int* __restrict__ cursor, int* __restrict__ csr_src, int E) {
    int e = blockIdx.x * blockDim.x + threadIdx.x;
    if (e < E) {
        int pos = atomicAdd(&cursor[edst[e]], 1);
        csr_src[pos] = esrc[e];
    }
}

// ---------- embedding lookup ----------
__global__ void embed_kernel(const int* __restrict__ tokens, const float* __restrict__ emb,
                             float* __restrict__ h, int N) {
    int t = blockIdx.x * blockDim.x + threadIdx.x;
    int n = t >> 4, c = t & 15;
    if (n < N) {
        int tok = tokens[n];
        ((float4*)h)[(size_t)n * 16 + c] = ((const float4*)emb)[(size_t)tok * 16 + c];
    }
}

// ---------- pull-mode aggregation: 16 lanes per dst node, no atomics ----------
__global__ void agg_csr_kernel(const int* __restrict__ rp, const int* __restrict__ deg,
                               const int* __restrict__ csr_src, const float* __restrict__ h,
                               float* __restrict__ agg, int N) {
    int t = blockIdx.x * blockDim.x + threadIdx.x;
    int n = t >> 4, c = t & 15;
    if (n >= N) return;
    int beg = rp[n], end = beg + deg[n];
    float ax = 0.f, ay = 0.f, az = 0.f, aw = 0.f;
    for (int e = beg; e < end; ++e) {
        int s = csr_src[e];
        float4 v = ((const float4*)h)[(size_t)s * 16 + c];
        ax += v.x; ay += v.y; az += v.z; aw += v.w;
    }
    float4 o = {ax, ay, az, aw};
    ((float4*)agg)[(size_t)n * 16 + c] = o;
}

// ---------- per-node GEMM: out[n] = relu(inv_deg*(agg[n]@W) + b), 1 thread/node ----------
__global__ void gemm_relu_kernel(const float* __restrict__ agg, const int* __restrict__ deg,
                                 const float* __restrict__ W, const float* __restrict__ b,
                                 float* __restrict__ out, int N) {
    __shared__ float4 Ws[64 * 16];
    __shared__ float4 bs[16];
    for (int i = threadIdx.x; i < 64 * 16; i += blockDim.x) Ws[i] = ((const float4*)W)[i];
    if (threadIdx.x < 16) bs[threadIdx.x] = ((const float4*)b)[threadIdx.x];
    __syncthreads();
    int n = blockIdx.x * blockDim.x + threadIdx.x;
    if (n >= N) return;
    float inv = 1.0f / fmaxf((float)deg[n], 1.0f);
    float4 hv[16];
    #pragma unroll
    for (int j = 0; j < 16; ++j) hv[j] = ((const float4*)agg)[(size_t)n * 16 + j];
    float4 acc[16];
    #pragma unroll
    for (int j = 0; j < 16; ++j) { acc[j].x = 0.f; acc[j].y = 0.f; acc[j].z = 0.f; acc[j].w = 0.f; }
    #pragma unroll
    for (int k4 = 0; k4 < 16; ++k4) {
        float4 hq = hv[k4];
        #pragma unroll
        for (int kk = 0; kk < 4; ++kk) {
            float hk = (kk == 0) ? hq.x : (kk == 1) ? hq.y : (kk == 2) ? hq.z : hq.w;
            int k = k4 * 4 + kk;
            #pragma unroll
            for (int j = 0; j < 16; ++j) {
                float4 w = Ws[k * 16 + j];
                acc[j].x = fmaf(hk, w.x, acc[j].x);
                acc[j].y = fmaf(hk, w.y, acc[j].y);
                acc[j].z = fmaf(hk, w.z, acc[j].z);
                acc[j].w = fmaf(hk, w.w, acc[j].w);
            }
        }
    }
    #pragma unroll
    for (int j = 0; j < 16; ++j) {
        float4 bb = bs[j];
        float4 o;
        o.x = fmaxf(fmaf(inv, acc[j].x, bb.x), 0.f);
        o.y = fmaxf(fmaf(inv, acc[j].y, bb.y), 0.f);
        o.z = fmaxf(fmaf(inv, acc[j].z, bb.z), 0.f);
        o.w = fmaxf(fmaf(inv, acc[j].w, bb.w), 0.f);
        ((float4*)out)[(size_t)n * 16 + j] = o;
    }
}

// ---------- fused mean-pool + classifier head: one block per graph ----------
__device__ __forceinline__ int lower_bound_i(const int* a, int n, int key) {
    int lo = 0, hi = n;
    while (lo < hi) {
        int mid = (lo + hi) >> 1;
        if (a[mid] < key) lo = mid + 1; else hi = mid;
    }
    return lo;
}

__global__ void pool_head_kernel(const float* __restrict__ h, const int* __restrict__ gids,
                                 const float* __restrict__ Wc, const float* __restrict__ bc,
                                 float* __restrict__ out, int N) {
    __shared__ float4 red[256];
    __shared__ float hg[64];
    int g = blockIdx.x;
    int lo = lower_bound_i(gids, N, g);
    int hi = lower_bound_i(gids, N, g + 1);
    int r = threadIdx.x >> 4, c = threadIdx.x & 15;
    float ax = 0.f, ay = 0.f, az = 0.f, aw = 0.f;
    for (int n = lo + r; n < hi; n += 16) {
        float4 v = ((const float4*)h)[(size_t)n * 16 + c];
        ax += v.x; ay += v.y; az += v.z; aw += v.w;
    }
    float4 a = {ax, ay, az, aw};
    red[threadIdx.x] = a;
    __syncthreads();
    for (int s = 8; s > 0; s >>= 1) {
        if (r < s) {
            float4 m = red[r * 16 + c];
            float4 o = red[(r + s) * 16 + c];
            m.x += o.x; m.y += o.y; m.z += o.z; m.w += o.w;
            red[r * 16 + c] = m;
        }
        __syncthreads();
    }
    if (r == 0) {
        float icnt = 1.0f / fmaxf((float)(hi - lo), 1.0f);
        float4 m = red[c];
        hg[c * 4 + 0] = m.x * icnt;
        hg[c * 4 + 1] = m.y * icnt;
        hg[c * 4 + 2] = m.z * icnt;
        hg[c * 4 + 3] = m.w * icnt;
    }
    __syncthreads();
    if (threadIdx.x < CLS) {
        float s = bc[threadIdx.x];
        #pragma unroll
        for (int k = 0; k < 64; ++k) s = fmaf(hg[k], Wc[k * CLS + threadIdx.x], s);
        out[(size_t)g * CLS + threadIdx.x] = s;
    }
}

extern "C" void kernel_launch(void* const* d_in, const int* in_sizes, int n_in,
                              void* d_out, int out_size, void* d_ws, size_t ws_size,
                              hipStream_t stream) {
    const int*   tokens = (const int*)d_in[0];
    const int*   esrc   = (const int*)d_in[1];
    const int*   edst   = (const int*)d_in[2];
    const int*   gids   = (const int*)d_in[3];
    const float* emb    = (const float*)d_in[4];
    const float* W1     = (const float*)d_in[5];
    const float* b1     = (const float*)d_in[6];
    const float* W2     = (const float*)d_in[7];
    const float* b2     = (const float*)d_in[8];
    const float* Wc     = (const float*)d_in[9];
    const float* bc     = (const float*)d_in[10];
    int N = in_sizes[0];
    int E = in_sizes[1];
    float* out = (float*)d_out;

    // workspace layout:
    // h[N*64] f32 | agg[N*64] f32 | deg[N] i32 | rp[N] i32 | cursor[N] i32 | csr_src[E] i32 | bsum[128] i32
    float* h      = (float*)d_ws;
    float* agg    = h + (size_t)N * 64;
    int*   deg    = (int*)(agg + (size_t)N * 64);
    int*   rp     = deg + N;
    int*   cursor = rp + N;
    int*   csr    = cursor + N;
    int*   bsum   = csr + E;

    int NB = (N + SCAN_E - 1) / SCAN_E;  // scan blocks (<=128)

    hipMemsetAsync(deg, 0, (size_t)N * sizeof(int), stream);

    // ----- build CSR (by dst) -----
    deg_count_kernel<<<(E + 255) / 256, 256, 0, stream>>>(edst, deg, E);
    scan1_kernel<<<NB, SCAN_T, 0, stream>>>(deg, rp, bsum, N);
    scan2_kernel<<<1, 128, 0, stream>>>(bsum, NB);
    scan3_kernel<<<(N + 255) / 256, 256, 0, stream>>>(rp, bsum, N);
    hipMemcpyAsync(cursor, rp, (size_t)N * sizeof(int), hipMemcpyDeviceToDevice, stream);
    scatter_kernel<<<(E + 255) / 256, 256, 0, stream>>>(esrc, edst, cursor, csr, E);

    // ----- embedding -----
    embed_kernel<<<(N * 16 + 255) / 256, 256, 0, stream>>>(tokens, emb, h, N);

    // ----- layer 1 -----
    agg_csr_kernel<<<(N * 16 + 255) / 256, 256, 0, stream>>>(rp, deg, csr, h, agg, N);
    gemm_relu_kernel<<<(N + 255) / 256, 256, 0, stream>>>(agg, deg, W1, b1, h, N);

    // ----- layer 2 -----
    agg_csr_kernel<<<(N * 16 + 255) / 256, 256, 0, stream>>>(rp, deg, csr, h, agg, N);
    gemm_relu_kernel<<<(N + 255) / 256, 256, 0, stream>>>(agg, deg, W2, b2, h, N);

    // ----- pooling + head -----
    pool_head_kernel<<<128, 256, 0, stream>>>(h, gids, Wc, bc, out, N);
}

// Round 6
// 459.776 us; speedup vs baseline: 7.7256x; 1.1153x over previous
//
#include <hip/hip_runtime.h>

#define DIM 64
#define CLS 20
#define SCAN_T 256
#define SCAN_E 1024   // elements per scan block (4 per thread)
#define NBANDS 8      // dst bands == XCD count
#define BBLOCKS 1024  // banded kernels: 128 blocks per band

// ---------- banded degree count: band p handled only by blocks with bid%8==p ----------
__global__ void banded_count_kernel(const int* __restrict__ edst, int* __restrict__ deg,
                                    int N, int E) {
    int band   = blockIdx.x & (NBANDS - 1);
    int chunk  = blockIdx.x >> 3;
    int nchunk = gridDim.x >> 3;
    int bandSize = (N + NBANDS - 1) / NBANDS;
    int lo = band * bandSize;
    int hi = min(lo + bandSize, N);
    int per  = (E + nchunk - 1) / nchunk;
    int ebeg = chunk * per;
    int eend = min(ebeg + per, E);
    for (int e = ebeg + threadIdx.x; e < eend; e += blockDim.x) {
        int d = edst[e];
        if (d >= lo && d < hi) atomicAdd(&deg[d], 1);
    }
}

// ---------- banded CSR scatter: csr band region is contiguous & single-XCD dirty ----------
__global__ void banded_scatter_kernel(const int* __restrict__ esrc, const int* __restrict__ edst,
                                      int* __restrict__ cursor, int* __restrict__ csr_src,
                                      int N, int E) {
    int band   = blockIdx.x & (NBANDS - 1);
    int chunk  = blockIdx.x >> 3;
    int nchunk = gridDim.x >> 3;
    int bandSize = (N + NBANDS - 1) / NBANDS;
    int lo = band * bandSize;
    int hi = min(lo + bandSize, N);
    int per  = (E + nchunk - 1) / nchunk;
    int ebeg = chunk * per;
    int eend = min(ebeg + per, E);
    for (int e = ebeg + threadIdx.x; e < eend; e += blockDim.x) {
        int d = edst[e];
        int s = esrc[e];
        if (d >= lo && d < hi) {
            int pos = atomicAdd(&cursor[d], 1);
            csr_src[pos] = s;
        }
    }
}

// ---------- exclusive scan, step 1: per-block ----------
__global__ void scan1_kernel(const int* __restrict__ deg, int* __restrict__ rp,
                             int* __restrict__ bsum, int N) {
    __shared__ int sh[SCAN_T];
    int base = blockIdx.x * SCAN_E + threadIdx.x * 4;
    int v0 = (base + 0 < N) ? deg[base + 0] : 0;
    int v1 = (base + 1 < N) ? deg[base + 1] : 0;
    int v2 = (base + 2 < N) ? deg[base + 2] : 0;
    int v3 = (base + 3 < N) ? deg[base + 3] : 0;
    sh[threadIdx.x] = v0 + v1 + v2 + v3;
    __syncthreads();
    for (int off = 1; off < SCAN_T; off <<= 1) {
        int t = (threadIdx.x >= off) ? sh[threadIdx.x - off] : 0;
        __syncthreads();
        sh[threadIdx.x] += t;
        __syncthreads();
    }
    int run = (threadIdx.x > 0) ? sh[threadIdx.x - 1] : 0;
    if (base + 0 < N) rp[base + 0] = run; run += v0;
    if (base + 1 < N) rp[base + 1] = run; run += v1;
    if (base + 2 < N) rp[base + 2] = run; run += v2;
    if (base + 3 < N) rp[base + 3] = run;
    if (threadIdx.x == SCAN_T - 1) bsum[blockIdx.x] = sh[SCAN_T - 1];
}

// ---------- scan step 2: scan of block sums (single block, NB <= 128) ----------
__global__ void scan2_kernel(int* __restrict__ bsum, int NB) {
    __shared__ int sh[128];
    int v = (threadIdx.x < NB) ? bsum[threadIdx.x] : 0;
    sh[threadIdx.x] = v;
    __syncthreads();
    for (int off = 1; off < 128; off <<= 1) {
        int t = (threadIdx.x >= off) ? sh[threadIdx.x - off] : 0;
        __syncthreads();
        sh[threadIdx.x] += t;
        __syncthreads();
    }
    if (threadIdx.x < NB) bsum[threadIdx.x] = sh[threadIdx.x] - v;  // exclusive
}

// ---------- scan step 3: add block offsets; also init cursor = rp ----------
__global__ void scan3_kernel(int* __restrict__ rp, int* __restrict__ cursor,
                             const int* __restrict__ bsum, int N) {
    int i = blockIdx.x * blockDim.x + threadIdx.x;
    if (i < N) {
        int v = rp[i] + bsum[i >> 10];
        rp[i] = v;
        cursor[i] = v;
    }
}

// ---------- embedding lookup ----------
__global__ void embed_kernel(const int* __restrict__ tokens, const float* __restrict__ emb,
                             float* __restrict__ h, int N) {
    int t = blockIdx.x * blockDim.x + threadIdx.x;
    int n = t >> 4, c = t & 15;
    if (n < N) {
        int tok = tokens[n];
        ((float4*)h)[(size_t)n * 16 + c] = ((const float4*)emb)[(size_t)tok * 16 + c];
    }
}

// ---------- pull-mode aggregation: 16 lanes per dst node, no atomics ----------
__global__ void agg_csr_kernel(const int* __restrict__ rp, const int* __restrict__ deg,
                               const int* __restrict__ csr_src, const float* __restrict__ h,
                               float* __restrict__ agg, int N) {
    int t = blockIdx.x * blockDim.x + threadIdx.x;
    int n = t >> 4, c = t & 15;
    if (n >= N) return;
    int beg = rp[n], end = beg + deg[n];
    float ax = 0.f, ay = 0.f, az = 0.f, aw = 0.f;
    for (int e = beg; e < end; ++e) {
        int s = csr_src[e];
        float4 v = ((const float4*)h)[(size_t)s * 16 + c];
        ax += v.x; ay += v.y; az += v.z; aw += v.w;
    }
    float4 o = {ax, ay, az, aw};
    ((float4*)agg)[(size_t)n * 16 + c] = o;
}

// ---------- per-node GEMM: out[n] = relu(inv_deg*(agg[n]@W) + b), 1 thread/node ----------
__global__ void gemm_relu_kernel(const float* __restrict__ agg, const int* __restrict__ deg,
                                 const float* __restrict__ W, const float* __restrict__ b,
                                 float* __restrict__ out, int N) {
    __shared__ float4 Ws[64 * 16];
    __shared__ float4 bs[16];
    for (int i = threadIdx.x; i < 64 * 16; i += blockDim.x) Ws[i] = ((const float4*)W)[i];
    if (threadIdx.x < 16) bs[threadIdx.x] = ((const float4*)b)[threadIdx.x];
    __syncthreads();
    int n = blockIdx.x * blockDim.x + threadIdx.x;
    if (n >= N) return;
    float inv = 1.0f / fmaxf((float)deg[n], 1.0f);
    float4 hv[16];
    #pragma unroll
    for (int j = 0; j < 16; ++j) hv[j] = ((const float4*)agg)[(size_t)n * 16 + j];
    float4 acc[16];
    #pragma unroll
    for (int j = 0; j < 16; ++j) { acc[j].x = 0.f; acc[j].y = 0.f; acc[j].z = 0.f; acc[j].w = 0.f; }
    #pragma unroll
    for (int k4 = 0; k4 < 16; ++k4) {
        float4 hq = hv[k4];
        #pragma unroll
        for (int kk = 0; kk < 4; ++kk) {
            float hk = (kk == 0) ? hq.x : (kk == 1) ? hq.y : (kk == 2) ? hq.z : hq.w;
            int k = k4 * 4 + kk;
            #pragma unroll
            for (int j = 0; j < 16; ++j) {
                float4 w = Ws[k * 16 + j];
                acc[j].x = fmaf(hk, w.x, acc[j].x);
                acc[j].y = fmaf(hk, w.y, acc[j].y);
                acc[j].z = fmaf(hk, w.z, acc[j].z);
                acc[j].w = fmaf(hk, w.w, acc[j].w);
            }
        }
    }
    #pragma unroll
    for (int j = 0; j < 16; ++j) {
        float4 bb = bs[j];
        float4 o;
        o.x = fmaxf(fmaf(inv, acc[j].x, bb.x), 0.f);
        o.y = fmaxf(fmaf(inv, acc[j].y, bb.y), 0.f);
        o.z = fmaxf(fmaf(inv, acc[j].z, bb.z), 0.f);
        o.w = fmaxf(fmaf(inv, acc[j].w, bb.w), 0.f);
        ((float4*)out)[(size_t)n * 16 + j] = o;
    }
}

// ---------- fused mean-pool + classifier head: one block per graph ----------
__device__ __forceinline__ int lower_bound_i(const int* a, int n, int key) {
    int lo = 0, hi = n;
    while (lo < hi) {
        int mid = (lo + hi) >> 1;
        if (a[mid] < key) lo = mid + 1; else hi = mid;
    }
    return lo;
}

__global__ void pool_head_kernel(const float* __restrict__ h, const int* __restrict__ gids,
                                 const float* __restrict__ Wc, const float* __restrict__ bc,
                                 float* __restrict__ out, int N) {
    __shared__ float4 red[256];
    __shared__ float hg[64];
    int g = blockIdx.x;
    int lo = lower_bound_i(gids, N, g);
    int hi = lower_bound_i(gids, N, g + 1);
    int r = threadIdx.x >> 4, c = threadIdx.x & 15;
    float ax = 0.f, ay = 0.f, az = 0.f, aw = 0.f;
    for (int n = lo + r; n < hi; n += 16) {
        float4 v = ((const float4*)h)[(size_t)n * 16 + c];
        ax += v.x; ay += v.y; az += v.z; aw += v.w;
    }
    float4 a = {ax, ay, az, aw};
    red[threadIdx.x] = a;
    __syncthreads();
    for (int s = 8; s > 0; s >>= 1) {
        if (r < s) {
            float4 m = red[r * 16 + c];
            float4 o = red[(r + s) * 16 + c];
            m.x += o.x; m.y += o.y; m.z += o.z; m.w += o.w;
            red[r * 16 + c] = m;
        }
        __syncthreads();
    }
    if (r == 0) {
        float icnt = 1.0f / fmaxf((float)(hi - lo), 1.0f);
        float4 m = red[c];
        hg[c * 4 + 0] = m.x * icnt;
        hg[c * 4 + 1] = m.y * icnt;
        hg[c * 4 + 2] = m.z * icnt;
        hg[c * 4 + 3] = m.w * icnt;
    }
    __syncthreads();
    if (threadIdx.x < CLS) {
        float s = bc[threadIdx.x];
        #pragma unroll
        for (int k = 0; k < 64; ++k) s = fmaf(hg[k], Wc[k * CLS + threadIdx.x], s);
        out[(size_t)g * CLS + threadIdx.x] = s;
    }
}

extern "C" void kernel_launch(void* const* d_in, const int* in_sizes, int n_in,
                              void* d_out, int out_size, void* d_ws, size_t ws_size,
                              hipStream_t stream) {
    const int*   tokens = (const int*)d_in[0];
    const int*   esrc   = (const int*)d_in[1];
    const int*   edst   = (const int*)d_in[2];
    const int*   gids   = (const int*)d_in[3];
    const float* emb    = (const float*)d_in[4];
    const float* W1     = (const float*)d_in[5];
    const float* b1     = (const float*)d_in[6];
    const float* W2     = (const float*)d_in[7];
    const float* b2     = (const float*)d_in[8];
    const float* Wc     = (const float*)d_in[9];
    const float* bc     = (const float*)d_in[10];
    int N = in_sizes[0];
    int E = in_sizes[1];
    float* out = (float*)d_out;

    // workspace layout:
    // h[N*64] f32 | agg[N*64] f32 | deg[N] i32 | rp[N] i32 | cursor[N] i32 | csr_src[E] i32 | bsum[128] i32
    float* h      = (float*)d_ws;
    float* agg    = h + (size_t)N * 64;
    int*   deg    = (int*)(agg + (size_t)N * 64);
    int*   rp     = deg + N;
    int*   cursor = rp + N;
    int*   csr    = cursor + N;
    int*   bsum   = csr + E;

    int NB = (N + SCAN_E - 1) / SCAN_E;  // scan blocks (<=128)

    hipMemsetAsync(deg, 0, (size_t)N * sizeof(int), stream);

    // ----- build CSR (by dst), XCD-banded -----
    banded_count_kernel<<<BBLOCKS, 256, 0, stream>>>(edst, deg, N, E);
    scan1_kernel<<<NB, SCAN_T, 0, stream>>>(deg, rp, bsum, N);
    scan2_kernel<<<1, 128, 0, stream>>>(bsum, NB);
    scan3_kernel<<<(N + 255) / 256, 256, 0, stream>>>(rp, cursor, bsum, N);
    banded_scatter_kernel<<<BBLOCKS, 256, 0, stream>>>(esrc, edst, cursor, csr, N, E);

    // ----- embedding -----
    embed_kernel<<<(N * 16 + 255) / 256, 256, 0, stream>>>(tokens, emb, h, N);

    // ----- layer 1 -----
    agg_csr_kernel<<<(N * 16 + 255) / 256, 256, 0, stream>>>(rp, deg, csr, h, agg, N);
    gemm_relu_kernel<<<(N + 255) / 256, 256, 0, stream>>>(agg, deg, W1, b1, h, N);

    // ----- layer 2 -----
    agg_csr_kernel<<<(N * 16 + 255) / 256, 256, 0, stream>>>(rp, deg, csr, h, agg, N);
    gemm_relu_kernel<<<(N + 255) / 256, 256, 0, stream>>>(agg, deg, W2, b2, h, N);

    // ----- pooling + head -----
    pool_head_kernel<<<128, 256, 0, stream>>>(h, gids, Wc, bc, out, N);
}